// Round 20
// baseline (74.264 us; speedup 1.0000x reference)
//
#include <hip/hip_runtime.h>
#include <hip/hip_bf16.h>

// UnivariateFlowMixture: N=1e6 points, C=8 channels, L=8 layers, B=32 bins.
// Pipeline: build_tables (1 blk) -> grid_eval (2 threads/point, 4ch each,
// LDS f16 neighbor exchange, packed 64B rows) -> interp_fused ILP-2
// (each thread owns 2 points; both gathers issued at entry; per-POINT pool).
// Round 20: r17/r19 plateau (61.9/63.2/63.5) is insensitive to G/LDS/occ ->
// dependent-gather latency. ILP-2 doubles per-thread MLP: issue both x loads
// + both row gathers up front, then process halves sequentially.

#define TB 3.0f
#define NB 32
#define NC 8
#define NL 8
#define LN2 0.69314718055994530942f

#define GX0 -6.5f
#define GX1 6.5f
#define TZ 0.5f
#define TL 0.5f

#define PT_FLOATS (64 * 99)                  // 6336: 64 tables of 33|33|33
#define GP_FLOATS (PT_FLOATS + 72 + 72 + 8)  // + Sc | Bb | LJ  (6488 floats)
#define GP_BYTES  (GP_FLOATS * 4)            // 25952
#define TAB_OFF   26112                      // 64B-aligned (64*408)
#define CAPP 64                              // pooled points per block-half

__device__ __forceinline__ float softplusf(float v) {
    return fmaxf(v, 0.f) + log1pf(expf(-fabsf(v)));
}

__device__ __forceinline__ unsigned short f2h(float f) {
    _Float16 h = (_Float16)f;
    unsigned short u;
    __builtin_memcpy(&u, &h, 2);
    return u;
}
__device__ __forceinline__ float h2f(unsigned short u) {
    _Float16 h;
    __builtin_memcpy(&h, &u, 2);
    return (float)h;
}

__device__ __forceinline__ int bsearch32(const float* __restrict__ E, float xc) {
    int i = (xc >= E[16]) ? 16 : 0;
    i += (xc >= E[i + 8]) ? 8 : 0;
    i += (xc >= E[i + 4]) ? 4 : 0;
    i += (xc >= E[i + 2]) ? 2 : 0;
    i += (xc >= E[i + 1]) ? 1 : 0;
    return i;
}

// Tlc: [0..32] cumw edges, [33..65] cumh, [66..98] derivs (LDS or global)
__device__ __forceinline__ void spline_eval(const float* __restrict__ Tlc,
                                            float zc, float& zo, float& ldo) {
    const float* E  = Tlc;
    const float* Hc = Tlc + 33;
    const float* Dv = Tlc + 66;

    float xc = fminf(fmaxf(zc, -TB), TB);
    int i = bsearch32(E, xc);

    float xk  = E[i],  xk1 = E[i + 1];
    float yk  = Hc[i], yk1 = Hc[i + 1];
    float dk  = Dv[i], dk1 = Dv[i + 1];

    float wk    = xk1 - xk;
    float hk    = yk1 - yk;
    float invw  = __builtin_amdgcn_rcpf(wk);
    float delta = hk * invw;
    float th    = (xc - xk) * invw;
    float omt   = 1.f - th;
    float t1m   = th * omt;
    float th2   = th * th;

    float num    = hk * fmaf(delta, th2, dk * t1m);
    float den    = fmaf(fmaf(-2.f, delta, dk + dk1), t1m, delta);
    float invden = __builtin_amdgcn_rcpf(den);
    float y      = fmaf(num, invden, yk);

    float dt    = delta * t1m;
    float inner = fmaf(dk1, th2, fmaf(dk, omt * omt, dt + dt));
    float dnum  = (delta * delta) * inner;
    float r  = dnum * invden * invden;
    float ld = LN2 * __builtin_amdgcn_logf(r);

    bool inside = (zc >= -TB) && (zc <= TB);
    zo  = inside ? y : zc;
    ldo = inside ? ld : 0.f;
}

// exact chain for one (x, channel); T global (L2-hot)
__device__ __forceinline__ void exact_chain(const float* __restrict__ T,
                                            float xv, int c,
                                            float& zout, float& lout) {
    const float* ScT = T + PT_FLOATS;
    const float* BbT = ScT + 72;
    const float* LJT = BbT + 72;
    float zc = xv;
    float lacc = LJT[c];
#pragma unroll 1
    for (int l = 0; l < NL; ++l) {
        zc = (zc - BbT[l * 8 + c]) * ScT[l * 8 + c];
        float ld;
        spline_eval(T + (l * 8 + c) * 99, zc, zc, ld);
        lacc += ld;
    }
    zout = (zc - BbT[NL * 8 + c]) * ScT[NL * 8 + c];
    lout = lacc;
}

// ---------------- kernel 1: build tables once -> gparam ----------------
extern "C" __global__ void __launch_bounds__(256)
build_tables(const float* __restrict__ w, const float* __restrict__ h,
             const float* __restrict__ s, const float* __restrict__ bias,
             const float* __restrict__ lsc, float* __restrict__ gparam)
{
    __shared__ float T[PT_FLOATS];
    __shared__ float Sc[72], Bb[72], LJ[8];

    const int tid = threadIdx.x;

    if (tid < 64) {                       // widths -> cumw edges
        const int l = tid >> 3, c = tid & 7;
        float* cw = &T[tid * 99];
        const float* wr = w + (l * NC + c) * NB;
        float m = wr[0];
        for (int b = 1; b < NB; ++b) m = fmaxf(m, wr[b]);
        float sum = 0.f;
        for (int b = 0; b < NB; ++b) sum += expf(wr[b] - m);
        float inv = 1.f / sum;
        float acc = 0.f;
        cw[0] = -TB;
        for (int b = 0; b < NB; ++b) {
            acc += 1e-3f + (1.f - 1e-3f * NB) * (expf(wr[b] - m) * inv);
            cw[b + 1] = 6.f * acc - 3.f;
        }
        cw[NB] = TB;
    } else if (tid < 128) {               // heights -> cumh
        const int t = tid - 64;
        float* ch = &T[t * 99 + 33];
        const int l = t >> 3, c = t & 7;
        const float* hr = h + (l * NC + c) * NB;
        float m = hr[0];
        for (int b = 1; b < NB; ++b) m = fmaxf(m, hr[b]);
        float sum = 0.f;
        for (int b = 0; b < NB; ++b) sum += expf(hr[b] - m);
        float inv = 1.f / sum;
        float acc = 0.f;
        ch[0] = -TB;
        for (int b = 0; b < NB; ++b) {
            acc += 1e-3f + (1.f - 1e-3f * NB) * (expf(hr[b] - m) * inv);
            ch[b + 1] = 6.f * acc - 3.f;
        }
        ch[NB] = TB;
    } else if (tid < 192) {               // derivs
        const int t = tid - 128;
        const int l = t >> 3, c = t & 7;
        float* dv = &T[t * 99 + 66];
        const float* sr = s + (l * NC + c) * (NB - 1);
        const float cst = logf(expm1f(1.f - 1e-3f));
        const float dbound = 1e-3f + softplusf(cst);
        dv[0]  = dbound;
        dv[NB] = dbound;
        for (int k = 0; k < NB - 1; ++k)
            dv[k + 1] = 1e-3f + softplusf(sr[k]);
    }
    if (tid < 72) { Sc[tid] = expf(-lsc[tid]); Bb[tid] = bias[tid]; }
    if (tid < 8) {
        float a = 0.f;
        for (int l = 0; l <= NL; ++l) a += lsc[l * NC + tid];
        LJ[tid] = -a;
    }
    __syncthreads();

    for (int k = tid; k < PT_FLOATS; k += 256) gparam[k] = T[k];
    if (tid < 72) gparam[PT_FLOATS + tid]       = Sc[tid];
    if (tid < 72) gparam[PT_FLOATS + 72 + tid]  = Bb[tid];
    if (tid < 8)  gparam[PT_FLOATS + 144 + tid] = LJ[tid];
}

// ------- kernel 2: grid eval, 2 threads/point (4 channels each) ------------
// Block covers 128 points with 1 overlap: rows [b*127, b*127+126] written.
extern "C" __global__ void __launch_bounds__(256)
grid_eval(const float* __restrict__ gparam, char* __restrict__ tabb,
          int G, float dx)
{
    __shared__ float T[GP_FLOATS];
    __shared__ unsigned short ZL[128 * 16];   // h(z)[8] | h(lj)[8] per point
    for (int k = threadIdx.x; k < GP_FLOATS; k += 256) T[k] = gparam[k];
    __syncthreads();
    const float* ScT = T + PT_FLOATS;
    const float* BbT = ScT + 72;
    const float* LJT = BbT + 72;

    const int pl = threadIdx.x & 127;
    const int c0 = (threadIdx.x >> 7) * 4;    // 0 or 4
    const int p0 = blockIdx.x * 127;
    const int i  = min(p0 + pl, G - 1);

    const float xv = fmaf((float)i, dx, GX0);
    float z[4], lj[4];
#pragma unroll
    for (int cc = 0; cc < 4; ++cc) { z[cc] = xv; lj[cc] = LJT[c0 + cc]; }

#pragma unroll 1
    for (int l = 0; l < NL; ++l) {
        const float* Tl = T + l * NC * 99;
#pragma unroll
        for (int cc = 0; cc < 4; ++cc) {
            const int c = c0 + cc;
            float u = (z[cc] - BbT[l * 8 + c]) * ScT[l * 8 + c];
            float zo, ld;
            spline_eval(Tl + c * 99, u, zo, ld);
            z[cc] = zo;
            lj[cc] += ld;
        }
    }
    unsigned short zh[4], lh[4];
#pragma unroll
    for (int cc = 0; cc < 4; ++cc) {
        const int c = c0 + cc;
        z[cc] = (z[cc] - BbT[NL * 8 + c]) * ScT[NL * 8 + c];
        zh[cc] = f2h(z[cc]);
        lh[cc] = f2h(lj[cc]);
        ZL[pl * 16 + c]     = zh[cc];
        ZL[pl * 16 + 8 + c] = lh[cc];
    }
    __syncthreads();

    const int r = p0 + pl;
    if (pl < 127 && r <= G - 2) {
        ushort4* rowp = (ushort4*)(tabb + (size_t)r * 64);
#pragma unroll
        for (int cc = 0; cc < 4; ++cc) {
            const int c = c0 + cc;
            const float zn  = h2f(ZL[(pl + 1) * 16 + c]);
            const float ljn = h2f(ZL[(pl + 1) * 16 + 8 + c]);
            ushort4 v;
            v.x = zh[cc]; v.y = f2h(zn - h2f(zh[cc]));
            v.z = lh[cc]; v.w = f2h(ljn - h2f(lh[cc]));
            rowp[c] = v;
        }
    }
}

// ------- kernel 3: fused interp ILP-2 (2 points/thread) + per-POINT pool ----
// Thread owns points n0 = blk*256+tid and n1 = n0 + H. Both x loads and both
// row gathers issued at entry (4 independent mem ops). Halves processed
// sequentially with the proven r17 pool pipeline (exact from L2-hot gparam).
extern "C" __global__ void __launch_bounds__(256)
interp_kernel(const float* __restrict__ x, const char* __restrict__ tabb,
              const float* __restrict__ gparam, float* __restrict__ out,
              int N, int H, int G, float dx, float invdx)
{
    __shared__ float xbuf[256];
    __shared__ unsigned char pool[CAPP];
    __shared__ float resZ[CAPP * 8], resL[CAPP * 8];
    __shared__ unsigned wcnt[4];

    const int tid  = threadIdx.x;
    const int lane = tid & 63;
    const int wloc = tid >> 6;
    const int n0   = blockIdx.x * 256 + tid;
    const int n1   = n0 + H;

    // ---- issue all 4 independent loads up front ----
    float xvA = 0.f, xvB = 0.f;
    if (n0 < N) xvA = x[n0];
    if (n1 < N) xvB = x[n1];
    int iA = (int)floorf((xvA - GX0) * invdx);
    int iB = (int)floorf((xvB - GX0) * invdx);
    iA = min(max(iA, 0), G - 2);
    iB = min(max(iB, 0), G - 2);
    union RowU { float4 q[4]; unsigned int u[16]; };
    RowU RA, RB;
    {
        const float4* rpA = (const float4*)(tabb + (size_t)iA * 64);
        const float4* rpB = (const float4*)(tabb + (size_t)iB * 64);
        RA.q[0] = rpA[0]; RA.q[1] = rpA[1];
        RB.q[0] = rpB[0]; RB.q[1] = rpB[1];
        RA.q[2] = rpA[2]; RA.q[3] = rpA[3];
        RB.q[2] = rpB[2]; RB.q[3] = rpB[3];
    }

#pragma unroll 1
    for (int half = 0; half < 2; ++half) {
        const int n = half ? n1 : n0;
        const float xv = half ? xvB : xvA;
        const int i = half ? iB : iA;
        const RowU& R = half ? RB : RA;
        const bool active = (n < N);

        xbuf[tid] = xv;

        float z[NC], lj[NC];
        bool pflag = false;
        if (active) {
            const bool oor = !(xv > GX0 && xv < GX1);
            const float t = (xv - fmaf((float)i, dx, GX0)) * invdx;
            int flags = 0;
#pragma unroll
            for (int c = 0; c < NC; ++c) {
                const unsigned a = R.u[2 * c], b = R.u[2 * c + 1];
                const float z0 = h2f((unsigned short)a);
                const float dz = h2f((unsigned short)(a >> 16));
                const float l0 = h2f((unsigned short)b);
                const float dl = h2f((unsigned short)(b >> 16));
                z[c]  = fmaf(t, dz, z0);
                lj[c] = fmaf(t, dl, l0);
                if (fabsf(dz) > TZ || fabsf(dl) > TL) flags = 1;
            }
            pflag = oor || (flags != 0);
        }

        // per-point pooling: one ballot, deterministic, no atomics
        const unsigned long long m = __ballot(pflag);
        if (lane == 0) wcnt[wloc] = (unsigned)__popcll(m);
        __syncthreads();                  // wcnt + xbuf visible

        unsigned woff = 0, btot = 0;
#pragma unroll
        for (int j = 0; j < 4; ++j) {
            const unsigned v = wcnt[j];
            if (j < wloc) woff += v;
            btot += v;
        }
        const unsigned idx = woff +
            (unsigned)__popcll(m & ((1ull << lane) - 1ull));
        if (pflag && idx < CAPP) pool[idx] = (unsigned char)tid;
        __syncthreads();                  // pool visible

        const unsigned pcnt = min(btot, (unsigned)CAPP);
        for (unsigned k = tid; k < pcnt * 8u; k += 256) {
            const int pt = (int)pool[k >> 3];
            const int cc = (int)(k & 7u);
            float zo, lo;
            exact_chain(gparam, xbuf[pt], cc, zo, lo);
            resZ[k] = zo; resL[k] = lo;
        }
        __syncthreads();                  // results visible

        if (pflag) {
            if (idx < CAPP) {
#pragma unroll
                for (int c = 0; c < NC; ++c) {
                    z[c]  = resZ[idx * 8 + c];
                    lj[c] = resL[idx * 8 + c];
                }
            } else {                      // pool overflow: inline exact
#pragma unroll 1
                for (int c = 0; c < NC; ++c)
                    exact_chain(gparam, xv, c, z[c], lj[c]);
            }
        }

        if (active) {
            float4* oz = (float4*)(out + (size_t)n * NC);
            oz[0] = make_float4(z[0], z[1], z[2], z[3]);
            oz[1] = make_float4(z[4], z[5], z[6], z[7]);
            float4* ol = (float4*)(out + (size_t)N * NC + (size_t)n * NC);
            ol[0] = make_float4(lj[0], lj[1], lj[2], lj[3]);
            ol[1] = make_float4(lj[4], lj[5], lj[6], lj[7]);
        }
        __syncthreads();                  // protect pool/res reuse
    }
}

// ---------------- legacy monolithic kernel (ws-too-small fallback) ----------
extern "C" __global__ void __launch_bounds__(256)
flow_kernel(const float* __restrict__ x, const float* __restrict__ w,
            const float* __restrict__ h, const float* __restrict__ s,
            const float* __restrict__ bias, const float* __restrict__ lsc,
            float* __restrict__ out, int N)
{
    __shared__ float T[PT_FLOATS];
    __shared__ float Bb[NL + 1][NC];
    __shared__ float Sc[NL + 1][NC];
    __shared__ float LJC[NC];

    const int tid = threadIdx.x;
    if (tid < 64) {
        const int l = tid >> 3, c = tid & 7;
        float* cw = &T[tid * 99];
        {
            const float* wr = w + (l * NC + c) * NB;
            float m = wr[0];
            for (int b = 1; b < NB; ++b) m = fmaxf(m, wr[b]);
            float sum = 0.f;
            for (int b = 0; b < NB; ++b) sum += expf(wr[b] - m);
            float inv = 1.f / sum;
            float acc = 0.f;
            cw[0] = -TB;
            for (int b = 0; b < NB; ++b) {
                acc += 1e-3f + (1.f - 1e-3f * NB) * (expf(wr[b] - m) * inv);
                cw[b + 1] = 6.f * acc - 3.f;
            }
            cw[NB] = TB;
        }
        {
            float* ch = cw + 33;
            const float* hr = h + (l * NC + c) * NB;
            float m = hr[0];
            for (int b = 1; b < NB; ++b) m = fmaxf(m, hr[b]);
            float sum = 0.f;
            for (int b = 0; b < NB; ++b) sum += expf(hr[b] - m);
            float inv = 1.f / sum;
            float acc = 0.f;
            ch[0] = -TB;
            for (int b = 0; b < NB; ++b) {
                acc += 1e-3f + (1.f - 1e-3f * NB) * (expf(hr[b] - m) * inv);
                ch[b + 1] = 6.f * acc - 3.f;
            }
            ch[NB] = TB;
        }
        {
            float* dv = cw + 66;
            const float* sr = s + (l * NC + c) * (NB - 1);
            const float cst = logf(expm1f(1.f - 1e-3f));
            const float dbound = 1e-3f + softplusf(cst);
            dv[0]  = dbound;
            dv[NB] = dbound;
            for (int k = 0; k < NB - 1; ++k)
                dv[k + 1] = 1e-3f + softplusf(sr[k]);
        }
    }
    if (tid < (NL + 1) * NC) {
        const int l = tid >> 3, c = tid & 7;
        Bb[l][c] = bias[tid];
        Sc[l][c] = expf(-lsc[tid]);
    }
    if (tid < NC) {
        float a = 0.f;
        for (int l = 0; l <= NL; ++l) a += lsc[l * NC + tid];
        LJC[tid] = -a;
    }
    __syncthreads();

    const int n = blockIdx.x * 256 + tid;
    if (n >= N) return;
    const float xv = x[n];
    float z[NC], lj[NC];
#pragma unroll
    for (int c = 0; c < NC; ++c) { z[c] = xv; lj[c] = LJC[c]; }
#pragma unroll 1
    for (int l = 0; l < NL; ++l) {
        const float* Tl = &T[l * NC * 99];
#pragma unroll
        for (int c = 0; c < NC; ++c) {
            float zc = (z[c] - Bb[l][c]) * Sc[l][c];
            float zo, ld;
            spline_eval(Tl + c * 99, zc, zo, ld);
            z[c] = zo;
            lj[c] += ld;
        }
    }
#pragma unroll
    for (int c = 0; c < NC; ++c) z[c] = (z[c] - Bb[NL][c]) * Sc[NL][c];

    float4* oz = (float4*)(out + (size_t)n * NC);
    oz[0] = make_float4(z[0], z[1], z[2], z[3]);
    oz[1] = make_float4(z[4], z[5], z[6], z[7]);
    float4* ol = (float4*)(out + (size_t)N * NC + (size_t)n * NC);
    ol[0] = make_float4(lj[0], lj[1], lj[2], lj[3]);
    ol[1] = make_float4(lj[4], lj[5], lj[6], lj[7]);
}

extern "C" void kernel_launch(void* const* d_in, const int* in_sizes, int n_in,
                              void* d_out, int out_size, void* d_ws, size_t ws_size,
                              hipStream_t stream) {
    const float* x    = (const float*)d_in[0];
    const float* w    = (const float*)d_in[1];
    const float* h    = (const float*)d_in[2];
    const float* s    = (const float*)d_in[3];
    const float* bias = (const float*)d_in[4];
    const float* lsc  = (const float*)d_in[5];
    float* out = (float*)d_out;
    const int N = in_sizes[0];

    // Layout (bytes): [0,GP_BYTES) gparam | [TAB_OFF,+G*64) packed tab
    int G = 65536;
    while (G > 2048 && ((size_t)TAB_OFF + (size_t)G * 64) > ws_size)
        G >>= 1;
    const size_t need = (size_t)TAB_OFF + (size_t)G * 64;

    if (need <= ws_size) {
        char* basep = (char*)d_ws;
        float* gparam = (float*)basep;
        char*  tabb   = basep + TAB_OFF;

        const float dx = (GX1 - GX0) / (float)(G - 1);
        const int gblocks = (G - 1 + 126) / 127;
        const int iblocks = (N / 2 + 255) / 256;   // each block covers 512 pts
        const int H       = iblocks * 256;         // second-half offset
        build_tables<<<1, 256, 0, stream>>>(w, h, s, bias, lsc, gparam);
        grid_eval<<<gblocks, 256, 0, stream>>>(gparam, tabb, G, dx);
        interp_kernel<<<iblocks, 256, 0, stream>>>(
            x, tabb, gparam, out, N, H, G, dx, 1.f / dx);
    } else {
        flow_kernel<<<(N + 255) / 256, 256, 0, stream>>>(
            x, w, h, s, bias, lsc, out, N);
    }
}

// Round 21
// 61.518 us; speedup vs baseline: 1.2072x; 1.2072x over previous
//
#include <hip/hip_runtime.h>
#include <hip/hip_bf16.h>

// UnivariateFlowMixture: N=1e6 points, C=8 channels, L=8 layers, B=32 bins.
// Pipeline: build_tables (1 blk) -> grid_eval (2 threads/point, 4ch each,
// LDS f16 neighbor exchange, packed 64B rows) -> interp_fused (1 thread/point
// lerp + per-POINT block pool + in-kernel exact, zero atomics).
// Round 21: byte-for-byte restore of round 17 (session best, 61.9us).
// r18 (G=32K), r19 (no LDS staging), r20 (ILP-2) all measured worse/equal.

#define TB 3.0f
#define NB 32
#define NC 8
#define NL 8
#define LN2 0.69314718055994530942f

#define GX0 -6.5f
#define GX1 6.5f
#define TZ 0.5f
#define TL 0.5f

#define PT_FLOATS (64 * 99)                  // 6336: 64 tables of 33|33|33
#define GP_FLOATS (PT_FLOATS + 72 + 72 + 8)  // + Sc | Bb | LJ  (6488 floats)
#define GP_BYTES  (GP_FLOATS * 4)            // 25952
#define TAB_OFF   26112                      // 64B-aligned (64*408)
#define CAPP 64                              // pooled points per block

__device__ __forceinline__ float softplusf(float v) {
    return fmaxf(v, 0.f) + log1pf(expf(-fabsf(v)));
}

__device__ __forceinline__ unsigned short f2h(float f) {
    _Float16 h = (_Float16)f;
    unsigned short u;
    __builtin_memcpy(&u, &h, 2);
    return u;
}
__device__ __forceinline__ float h2f(unsigned short u) {
    _Float16 h;
    __builtin_memcpy(&h, &u, 2);
    return (float)h;
}

__device__ __forceinline__ int bsearch32(const float* __restrict__ E, float xc) {
    int i = (xc >= E[16]) ? 16 : 0;
    i += (xc >= E[i + 8]) ? 8 : 0;
    i += (xc >= E[i + 4]) ? 4 : 0;
    i += (xc >= E[i + 2]) ? 2 : 0;
    i += (xc >= E[i + 1]) ? 1 : 0;
    return i;
}

// Tlc: [0..32] cumw edges, [33..65] cumh, [66..98] derivs (LDS or global)
__device__ __forceinline__ void spline_eval(const float* __restrict__ Tlc,
                                            float zc, float& zo, float& ldo) {
    const float* E  = Tlc;
    const float* Hc = Tlc + 33;
    const float* Dv = Tlc + 66;

    float xc = fminf(fmaxf(zc, -TB), TB);
    int i = bsearch32(E, xc);

    float xk  = E[i],  xk1 = E[i + 1];
    float yk  = Hc[i], yk1 = Hc[i + 1];
    float dk  = Dv[i], dk1 = Dv[i + 1];

    float wk    = xk1 - xk;
    float hk    = yk1 - yk;
    float invw  = __builtin_amdgcn_rcpf(wk);
    float delta = hk * invw;
    float th    = (xc - xk) * invw;
    float omt   = 1.f - th;
    float t1m   = th * omt;
    float th2   = th * th;

    float num    = hk * fmaf(delta, th2, dk * t1m);
    float den    = fmaf(fmaf(-2.f, delta, dk + dk1), t1m, delta);
    float invden = __builtin_amdgcn_rcpf(den);
    float y      = fmaf(num, invden, yk);

    float dt    = delta * t1m;
    float inner = fmaf(dk1, th2, fmaf(dk, omt * omt, dt + dt));
    float dnum  = (delta * delta) * inner;
    float r  = dnum * invden * invden;
    float ld = LN2 * __builtin_amdgcn_logf(r);

    bool inside = (zc >= -TB) && (zc <= TB);
    zo  = inside ? y : zc;
    ldo = inside ? ld : 0.f;
}

// exact chain for one (x, channel) from LDS-staged T
__device__ __forceinline__ void exact_chain(const float* __restrict__ T,
                                            float xv, int c,
                                            float& zout, float& lout) {
    const float* ScT = T + PT_FLOATS;
    const float* BbT = ScT + 72;
    const float* LJT = BbT + 72;
    float zc = xv;
    float lacc = LJT[c];
#pragma unroll 1
    for (int l = 0; l < NL; ++l) {
        zc = (zc - BbT[l * 8 + c]) * ScT[l * 8 + c];
        float ld;
        spline_eval(T + (l * 8 + c) * 99, zc, zc, ld);
        lacc += ld;
    }
    zout = (zc - BbT[NL * 8 + c]) * ScT[NL * 8 + c];
    lout = lacc;
}

// ---------------- kernel 1: build tables once -> gparam ----------------
extern "C" __global__ void __launch_bounds__(256)
build_tables(const float* __restrict__ w, const float* __restrict__ h,
             const float* __restrict__ s, const float* __restrict__ bias,
             const float* __restrict__ lsc, float* __restrict__ gparam)
{
    __shared__ float T[PT_FLOATS];
    __shared__ float Sc[72], Bb[72], LJ[8];

    const int tid = threadIdx.x;

    if (tid < 64) {                       // widths -> cumw edges
        const int l = tid >> 3, c = tid & 7;
        float* cw = &T[tid * 99];
        const float* wr = w + (l * NC + c) * NB;
        float m = wr[0];
        for (int b = 1; b < NB; ++b) m = fmaxf(m, wr[b]);
        float sum = 0.f;
        for (int b = 0; b < NB; ++b) sum += expf(wr[b] - m);
        float inv = 1.f / sum;
        float acc = 0.f;
        cw[0] = -TB;
        for (int b = 0; b < NB; ++b) {
            acc += 1e-3f + (1.f - 1e-3f * NB) * (expf(wr[b] - m) * inv);
            cw[b + 1] = 6.f * acc - 3.f;
        }
        cw[NB] = TB;
    } else if (tid < 128) {               // heights -> cumh
        const int t = tid - 64;
        float* ch = &T[t * 99 + 33];
        const int l = t >> 3, c = t & 7;
        const float* hr = h + (l * NC + c) * NB;
        float m = hr[0];
        for (int b = 1; b < NB; ++b) m = fmaxf(m, hr[b]);
        float sum = 0.f;
        for (int b = 0; b < NB; ++b) sum += expf(hr[b] - m);
        float inv = 1.f / sum;
        float acc = 0.f;
        ch[0] = -TB;
        for (int b = 0; b < NB; ++b) {
            acc += 1e-3f + (1.f - 1e-3f * NB) * (expf(hr[b] - m) * inv);
            ch[b + 1] = 6.f * acc - 3.f;
        }
        ch[NB] = TB;
    } else if (tid < 192) {               // derivs
        const int t = tid - 128;
        const int l = t >> 3, c = t & 7;
        float* dv = &T[t * 99 + 66];
        const float* sr = s + (l * NC + c) * (NB - 1);
        const float cst = logf(expm1f(1.f - 1e-3f));
        const float dbound = 1e-3f + softplusf(cst);
        dv[0]  = dbound;
        dv[NB] = dbound;
        for (int k = 0; k < NB - 1; ++k)
            dv[k + 1] = 1e-3f + softplusf(sr[k]);
    }
    if (tid < 72) { Sc[tid] = expf(-lsc[tid]); Bb[tid] = bias[tid]; }
    if (tid < 8) {
        float a = 0.f;
        for (int l = 0; l <= NL; ++l) a += lsc[l * NC + tid];
        LJ[tid] = -a;
    }
    __syncthreads();

    for (int k = tid; k < PT_FLOATS; k += 256) gparam[k] = T[k];
    if (tid < 72) gparam[PT_FLOATS + tid]       = Sc[tid];
    if (tid < 72) gparam[PT_FLOATS + 72 + tid]  = Bb[tid];
    if (tid < 8)  gparam[PT_FLOATS + 144 + tid] = LJ[tid];
}

// ------- kernel 2: grid eval, 2 threads/point (4 channels each) ------------
// Block covers 128 points with 1 overlap: rows [b*127, b*127+126] written.
// thread: pl = tid&127, c0 = (tid>>7)*4. Neighbor exchange via f16 LDS.
extern "C" __global__ void __launch_bounds__(256)
grid_eval(const float* __restrict__ gparam, char* __restrict__ tabb,
          int G, float dx)
{
    __shared__ float T[GP_FLOATS];
    __shared__ unsigned short ZL[128 * 16];   // h(z)[8] | h(lj)[8] per point
    for (int k = threadIdx.x; k < GP_FLOATS; k += 256) T[k] = gparam[k];
    __syncthreads();
    const float* ScT = T + PT_FLOATS;
    const float* BbT = ScT + 72;
    const float* LJT = BbT + 72;

    const int pl = threadIdx.x & 127;
    const int c0 = (threadIdx.x >> 7) * 4;    // 0 or 4
    const int p0 = blockIdx.x * 127;
    const int i  = min(p0 + pl, G - 1);

    const float xv = fmaf((float)i, dx, GX0);
    float z[4], lj[4];
#pragma unroll
    for (int cc = 0; cc < 4; ++cc) { z[cc] = xv; lj[cc] = LJT[c0 + cc]; }

#pragma unroll 1
    for (int l = 0; l < NL; ++l) {
        const float* Tl = T + l * NC * 99;
#pragma unroll
        for (int cc = 0; cc < 4; ++cc) {
            const int c = c0 + cc;
            float u = (z[cc] - BbT[l * 8 + c]) * ScT[l * 8 + c];
            float zo, ld;
            spline_eval(Tl + c * 99, u, zo, ld);
            z[cc] = zo;
            lj[cc] += ld;
        }
    }
    unsigned short zh[4], lh[4];
#pragma unroll
    for (int cc = 0; cc < 4; ++cc) {
        const int c = c0 + cc;
        z[cc] = (z[cc] - BbT[NL * 8 + c]) * ScT[NL * 8 + c];
        zh[cc] = f2h(z[cc]);
        lh[cc] = f2h(lj[cc]);
        ZL[pl * 16 + c]     = zh[cc];
        ZL[pl * 16 + 8 + c] = lh[cc];
    }
    __syncthreads();

    const int r = p0 + pl;
    if (pl < 127 && r <= G - 2) {
        ushort4* rowp = (ushort4*)(tabb + (size_t)r * 64);
#pragma unroll
        for (int cc = 0; cc < 4; ++cc) {
            const int c = c0 + cc;
            const float zn  = h2f(ZL[(pl + 1) * 16 + c]);
            const float ljn = h2f(ZL[(pl + 1) * 16 + 8 + c]);
            ushort4 v;
            v.x = zh[cc]; v.y = f2h(zn - h2f(zh[cc]));
            v.z = lh[cc]; v.w = f2h(ljn - h2f(lh[cc]));
            rowp[c] = v;
        }
    }
}

// ------- kernel 3: fused interp (1 thread/point) + per-POINT pool -----------
extern "C" __global__ void __launch_bounds__(256)
interp_kernel(const float* __restrict__ x, const char* __restrict__ tabb,
              const float* __restrict__ gparam, float* __restrict__ out,
              int N, int G, float dx, float invdx)
{
    __shared__ float T[GP_FLOATS];
    __shared__ float xbuf[256];
    __shared__ unsigned char pool[CAPP];
    __shared__ float resZ[CAPP * 8], resL[CAPP * 8];
    __shared__ unsigned wcnt[4];

    const int tid  = threadIdx.x;
    const int n    = blockIdx.x * 256 + tid;
    const int lane = tid & 63;
    const int wloc = tid >> 6;
    const bool active = (n < N);

    float xv = 0.f;
    if (active) xv = x[n];
    xbuf[tid] = xv;

    float z[NC], lj[NC];
    bool pflag = false;
    if (active) {
        int i = (int)floorf((xv - GX0) * invdx);
        const bool oor = !(xv > GX0 && xv < GX1);
        i = min(max(i, 0), G - 2);
        const float t = (xv - fmaf((float)i, dx, GX0)) * invdx;

        const float4* rp = (const float4*)(tabb + (size_t)i * 64);
        union { float4 q[4]; unsigned int u[16]; } R;
        R.q[0] = rp[0]; R.q[1] = rp[1]; R.q[2] = rp[2]; R.q[3] = rp[3];
        int flags = 0;
#pragma unroll
        for (int c = 0; c < NC; ++c) {
            const unsigned a = R.u[2 * c], b = R.u[2 * c + 1];
            const float z0 = h2f((unsigned short)a);
            const float dz = h2f((unsigned short)(a >> 16));
            const float l0 = h2f((unsigned short)b);
            const float dl = h2f((unsigned short)(b >> 16));
            z[c]  = fmaf(t, dz, z0);
            lj[c] = fmaf(t, dl, l0);
            if (fabsf(dz) > TZ || fabsf(dl) > TL) flags = 1;
        }
        pflag = oor || (flags != 0);
    }

    // per-point pooling: one ballot, deterministic, no atomics
    const unsigned long long m = __ballot(pflag);
    if (lane == 0) wcnt[wloc] = (unsigned)__popcll(m);
    __syncthreads();                      // wcnt + xbuf visible

    unsigned woff = 0, btot = 0;
#pragma unroll
    for (int j = 0; j < 4; ++j) {
        const unsigned v = wcnt[j];
        if (j < wloc) woff += v;
        btot += v;
    }
    const unsigned idx = woff +
        (unsigned)__popcll(m & ((1ull << lane) - 1ull));
    if (pflag && idx < CAPP) pool[idx] = (unsigned char)tid;
    if (btot > 0) {                       // stage tables only when needed
        for (int k = tid; k < GP_FLOATS; k += 256) T[k] = gparam[k];
    }
    __syncthreads();                      // pool + T visible

    const unsigned pcnt = min(btot, (unsigned)CAPP);
    for (unsigned k = tid; k < pcnt * 8u; k += 256) {
        const int pt = (int)pool[k >> 3];
        const int cc = (int)(k & 7u);
        float zo, lo;
        exact_chain(T, xbuf[pt], cc, zo, lo);
        resZ[k] = zo; resL[k] = lo;
    }
    __syncthreads();                      // results visible

    if (pflag) {
        if (idx < CAPP) {
#pragma unroll
            for (int c = 0; c < NC; ++c) {
                z[c]  = resZ[idx * 8 + c];
                lj[c] = resL[idx * 8 + c];
            }
        } else {                          // pool overflow: inline exact
#pragma unroll 1
            for (int c = 0; c < NC; ++c)
                exact_chain(T, xv, c, z[c], lj[c]);
        }
    }

    if (active) {
        float4* oz = (float4*)(out + (size_t)n * NC);
        oz[0] = make_float4(z[0], z[1], z[2], z[3]);
        oz[1] = make_float4(z[4], z[5], z[6], z[7]);
        float4* ol = (float4*)(out + (size_t)N * NC + (size_t)n * NC);
        ol[0] = make_float4(lj[0], lj[1], lj[2], lj[3]);
        ol[1] = make_float4(lj[4], lj[5], lj[6], lj[7]);
    }
}

// ---------------- legacy monolithic kernel (ws-too-small fallback) ----------
extern "C" __global__ void __launch_bounds__(256)
flow_kernel(const float* __restrict__ x, const float* __restrict__ w,
            const float* __restrict__ h, const float* __restrict__ s,
            const float* __restrict__ bias, const float* __restrict__ lsc,
            float* __restrict__ out, int N)
{
    __shared__ float T[PT_FLOATS];
    __shared__ float Bb[NL + 1][NC];
    __shared__ float Sc[NL + 1][NC];
    __shared__ float LJC[NC];

    const int tid = threadIdx.x;
    if (tid < 64) {
        const int l = tid >> 3, c = tid & 7;
        float* cw = &T[tid * 99];
        {
            const float* wr = w + (l * NC + c) * NB;
            float m = wr[0];
            for (int b = 1; b < NB; ++b) m = fmaxf(m, wr[b]);
            float sum = 0.f;
            for (int b = 0; b < NB; ++b) sum += expf(wr[b] - m);
            float inv = 1.f / sum;
            float acc = 0.f;
            cw[0] = -TB;
            for (int b = 0; b < NB; ++b) {
                acc += 1e-3f + (1.f - 1e-3f * NB) * (expf(wr[b] - m) * inv);
                cw[b + 1] = 6.f * acc - 3.f;
            }
            cw[NB] = TB;
        }
        {
            float* ch = cw + 33;
            const float* hr = h + (l * NC + c) * NB;
            float m = hr[0];
            for (int b = 1; b < NB; ++b) m = fmaxf(m, hr[b]);
            float sum = 0.f;
            for (int b = 0; b < NB; ++b) sum += expf(hr[b] - m);
            float inv = 1.f / sum;
            float acc = 0.f;
            ch[0] = -TB;
            for (int b = 0; b < NB; ++b) {
                acc += 1e-3f + (1.f - 1e-3f * NB) * (expf(hr[b] - m) * inv);
                ch[b + 1] = 6.f * acc - 3.f;
            }
            ch[NB] = TB;
        }
        {
            float* dv = cw + 66;
            const float* sr = s + (l * NC + c) * (NB - 1);
            const float cst = logf(expm1f(1.f - 1e-3f));
            const float dbound = 1e-3f + softplusf(cst);
            dv[0]  = dbound;
            dv[NB] = dbound;
            for (int k = 0; k < NB - 1; ++k)
                dv[k + 1] = 1e-3f + softplusf(sr[k]);
        }
    }
    if (tid < (NL + 1) * NC) {
        const int l = tid >> 3, c = tid & 7;
        Bb[l][c] = bias[tid];
        Sc[l][c] = expf(-lsc[tid]);
    }
    if (tid < NC) {
        float a = 0.f;
        for (int l = 0; l <= NL; ++l) a += lsc[l * NC + tid];
        LJC[tid] = -a;
    }
    __syncthreads();

    const int n = blockIdx.x * 256 + tid;
    if (n >= N) return;
    const float xv = x[n];
    float z[NC], lj[NC];
#pragma unroll
    for (int c = 0; c < NC; ++c) { z[c] = xv; lj[c] = LJC[c]; }
#pragma unroll 1
    for (int l = 0; l < NL; ++l) {
        const float* Tl = &T[l * NC * 99];
#pragma unroll
        for (int c = 0; c < NC; ++c) {
            float zc = (z[c] - Bb[l][c]) * Sc[l][c];
            float zo, ld;
            spline_eval(Tl + c * 99, zc, zo, ld);
            z[c] = zo;
            lj[c] += ld;
        }
    }
#pragma unroll
    for (int c = 0; c < NC; ++c) z[c] = (z[c] - Bb[NL][c]) * Sc[NL][c];

    float4* oz = (float4*)(out + (size_t)n * NC);
    oz[0] = make_float4(z[0], z[1], z[2], z[3]);
    oz[1] = make_float4(z[4], z[5], z[6], z[7]);
    float4* ol = (float4*)(out + (size_t)N * NC + (size_t)n * NC);
    ol[0] = make_float4(lj[0], lj[1], lj[2], lj[3]);
    ol[1] = make_float4(lj[4], lj[5], lj[6], lj[7]);
}

extern "C" void kernel_launch(void* const* d_in, const int* in_sizes, int n_in,
                              void* d_out, int out_size, void* d_ws, size_t ws_size,
                              hipStream_t stream) {
    const float* x    = (const float*)d_in[0];
    const float* w    = (const float*)d_in[1];
    const float* h    = (const float*)d_in[2];
    const float* s    = (const float*)d_in[3];
    const float* bias = (const float*)d_in[4];
    const float* lsc  = (const float*)d_in[5];
    float* out = (float*)d_out;
    const int N = in_sizes[0];

    // Layout (bytes): [0,GP_BYTES) gparam | [TAB_OFF,+G*64) packed tab
    int G = 65536;
    while (G > 2048 && ((size_t)TAB_OFF + (size_t)G * 64) > ws_size)
        G >>= 1;
    const size_t need = (size_t)TAB_OFF + (size_t)G * 64;

    if (need <= ws_size) {
        char* basep = (char*)d_ws;
        float* gparam = (float*)basep;
        char*  tabb   = basep + TAB_OFF;

        const float dx = (GX1 - GX0) / (float)(G - 1);
        const int gblocks = (G - 1 + 126) / 127;
        build_tables<<<1, 256, 0, stream>>>(w, h, s, bias, lsc, gparam);
        grid_eval<<<gblocks, 256, 0, stream>>>(gparam, tabb, G, dx);
        interp_kernel<<<(N + 255) / 256, 256, 0, stream>>>(
            x, tabb, gparam, out, N, G, dx, 1.f / dx);
    } else {
        flow_kernel<<<(N + 255) / 256, 256, 0, stream>>>(
            x, w, h, s, bias, lsc, out, N);
    }
}